// Round 11
// baseline (244.176 us; speedup 1.0000x reference)
//
#include <hip/hip_runtime.h>

#define D 64
#define LOG2E 1.4426950408889634f
#define NPART 8   // XCD count / privatization factor

typedef _Float16 hv2 __attribute__((ext_vector_type(2)));

__device__ __forceinline__ hv2 u2h(unsigned int u) { return __builtin_bit_cast(hv2, u); }
__device__ __forceinline__ unsigned int h2u(hv2 h) { return __builtin_bit_cast(unsigned int, h); }

__device__ __forceinline__ float fdot2f(hv2 a, hv2 b, float c) {
#if __has_builtin(__builtin_amdgcn_fdot2)
    return __builtin_amdgcn_fdot2(a, b, c, false);
#else
    return c + (float)a.x * (float)b.x + (float)a.y * (float)b.y;
#endif
}

__device__ __forceinline__ hv2 lrelu2(hv2 v) {      // packed leaky-relu(0.2)
    hv2 m = v * (_Float16)0.2f;
    hv2 r;
    r.x = v.x > (_Float16)0.f ? v.x : m.x;
    r.y = v.y > (_Float16)0.f ? v.y : m.y;
    return r;
}

// z = x@W^T+b (LDS-tiled, conflict-free) + fused 8-way-privatized degree count.
// Payload row (64 uints): u[2t]=f16x2{z_2t,z_2t+1}, u[2t+1]=f16x2{x_2t,x_2t+1}.
// deg8[(blockIdx%8)*n + d]: one XCD-class of blocks per copy -> no line ping-pong.
__global__ __launch_bounds__(256) void gemm_z_count(const float* __restrict__ x,
                                                    const float* __restrict__ W,
                                                    const float* __restrict__ b,
                                                    unsigned int* __restrict__ zxb,
                                                    int n,
                                                    const int* __restrict__ dst,
                                                    int* __restrict__ deg8,
                                                    int* __restrict__ slot,
                                                    int e_cnt) {
    __shared__ float wt[D * 65];   // wt[k*65+j] = W[j*D+k]
    __shared__ float xs[64 * D];
    int tid = threadIdx.x;

    // fused count: issue early, latency hides under GEMM
    int gtid = blockIdx.x * 256 + tid;
    int nthreads = gridDim.x * 256;
    int* mydeg = deg8 + (size_t)(blockIdx.x & (NPART - 1)) * n;
    int e0 = -1, e1 = -1, e2 = -1, s0 = 0, s1 = 0, s2 = 0;
    {
        int ee = gtid;
        if (ee < e_cnt) { e0 = ee; s0 = atomicAdd(&mydeg[dst[ee]], 1); ee += nthreads; }
        if (ee < e_cnt) { e1 = ee; s1 = atomicAdd(&mydeg[dst[ee]], 1); ee += nthreads; }
        if (ee < e_cnt) { e2 = ee; s2 = atomicAdd(&mydeg[dst[ee]], 1); }
    }

    for (int i = tid; i < D * D; i += 256) {
        int j = i >> 6, k = i & 63;
        wt[k * 65 + j] = W[i];
    }
    int row0 = blockIdx.x * 64;
    for (int i = tid; i < 64 * D / 4; i += 256) {
        int r = row0 + (i >> 4);
        float4 v = (r < n) ? ((const float4*)x)[(size_t)r * 16 + (i & 15)]
                           : make_float4(0.f, 0.f, 0.f, 0.f);
        ((float4*)xs)[i] = v;
    }
    __syncthreads();
    int col = tid & 63;
    int w   = tid >> 6;
    float bb = b[col];
    float acc[16];
#pragma unroll
    for (int r = 0; r < 16; ++r) acc[r] = bb;

    for (int k4 = 0; k4 < D; k4 += 4) {    // rolled: keep VGPR low
        float wv0 = wt[(k4 + 0) * 65 + col];
        float wv1 = wt[(k4 + 1) * 65 + col];
        float wv2 = wt[(k4 + 2) * 65 + col];
        float wv3 = wt[(k4 + 3) * 65 + col];
#pragma unroll
        for (int r = 0; r < 16; ++r) {
            const float4 xv = *(const float4*)&xs[(w * 16 + r) * D + k4];  // broadcast
            acc[r] += xv.x * wv0 + xv.y * wv1 + xv.z * wv2 + xv.w * wv3;
        }
    }
    bool odd = col & 1;
#pragma unroll
    for (int r = 0; r < 16; ++r) {
        int row = row0 + w * 16 + r;
        float z = acc[r];
        float xv = xs[(w * 16 + r) * D + col];
        float zsh = __shfl_xor(z, 1, 64);
        float xsh = __shfl_xor(xv, 1, 64);
        // even lane col: z-pair {z_col, z_col+1}; odd lane col: x-pair {x_col-1, x_col}
        float lo = odd ? xsh : z;
        float hi = odd ? xv : zsh;
        if (row < n) {
            hv2 hp;
            hp.x = (_Float16)lo;
            hp.y = (_Float16)hi;
            zxb[(size_t)row * 64 + col] = h2u(hp);     // coalesced 4B/lane
        }
    }

    if (e0 >= 0) slot[e0] = s0;
    if (e1 >= 0) slot[e1] = s1;
    if (e2 >= 0) slot[e2] = s2;
}

// ---- scan over 8 privatized copies ----
__global__ __launch_bounds__(256) void scan_part8(const int* __restrict__ deg8,
                                                  int* __restrict__ part, int n) {
    __shared__ int red[256];
    int t = threadIdx.x;
    int i = blockIdx.x * 256 + t;
    int s = 0;
    if (i < n)
#pragma unroll
        for (int c = 0; c < NPART; ++c) s += deg8[(size_t)c * n + i];
    red[t] = s;
    __syncthreads();
    for (int off = 128; off >= 1; off >>= 1) {
        if (t < off) red[t] += red[t + off];
        __syncthreads();
    }
    if (t == 0) part[blockIdx.x] = red[0];
}

__global__ __launch_bounds__(512) void scan_top(int* __restrict__ part, int B) {
    __shared__ int s[512];
    int t = threadIdx.x;
    int v = (t < B) ? part[t] : 0;
    s[t] = v;
    __syncthreads();
    for (int off = 1; off < 512; off <<= 1) {
        int u = (t >= off) ? s[t - off] : 0;
        __syncthreads();
        s[t] += u;
        __syncthreads();
    }
    if (t < B) part[t] = s[t] - v;   // exclusive
}

// rowstart + transform deg8 copies IN PLACE into per-copy bases
__global__ __launch_bounds__(256) void scan_final8(int* __restrict__ deg8,
                                                   const int* __restrict__ part,
                                                   int* __restrict__ rowstart, int n) {
    __shared__ int s[256];
    int t = threadIdx.x;
    int i = blockIdx.x * 256 + t;
    int dc[NPART];
    int tot = 0;
    if (i < n)
#pragma unroll
        for (int c = 0; c < NPART; ++c) { dc[c] = deg8[(size_t)c * n + i]; tot += dc[c]; }
    s[t] = tot;
    __syncthreads();
    for (int off = 1; off < 256; off <<= 1) {
        int u = (t >= off) ? s[t - off] : 0;
        __syncthreads();
        s[t] += u;
        __syncthreads();
    }
    int incl = s[t] + part[blockIdx.x];
    if (i < n) {
        int run = incl - tot;          // exclusive start for node i
        rowstart[i] = run;
#pragma unroll
        for (int c = 0; c < NPART; ++c) { int tmp = dc[c]; deg8[(size_t)c * n + i] = run; run += tmp; }
    }
    if (i == n - 1) rowstart[n] = incl;
}

// XCD-partitioned scatter: group g (blockIdx % 8) writes only dst in its node
// range -> each srcids line owned by one group; no cross-XCD ping-pong.
// copy of edge e = ((e mod T) >> 8) & 7, matching gemm_z_count's assignment.
__global__ __launch_bounds__(256) void csr_fill_part(const int* __restrict__ src,
                                                     const int* __restrict__ dst,
                                                     const int* __restrict__ base8,
                                                     const int* __restrict__ slot,
                                                     int* __restrict__ srcids,
                                                     int e_cnt, int n, int T) {
    int g  = blockIdx.x & (NPART - 1);
    int gb = blockIdx.x >> 3;
    int gstride = (gridDim.x >> 3) * 256;
    int nper = (n + NPART - 1) / NPART;
    int lo = g * nper, hi = min(lo + nper, n);
    for (int e = gb * 256 + threadIdx.x; e < e_cnt; e += gstride) {
        int d = dst[e];
        if (d < lo || d >= hi) continue;
        int em = e;
        while (em >= T) em -= T;             // e mod T (E < 3T)
        int c = (em >> 8) & (NPART - 1);
        srcids[base8[(size_t)c * n + d] + slot[e]] = src[e];
    }
}

// wave-per-node, quarter-wave per edge, 8 edges/iter; f16 packed math.
// row uint4 at 4q = {zpair(4q,4q+1), xpair(4q,4q+1), zpair(4q+2,4q+3), xpair(4q+2,4q+3)}
__global__ __launch_bounds__(256) void gather4h(const int* __restrict__ srcids,
                                                const int* __restrict__ rowstart,
                                                const unsigned int* __restrict__ zxb,
                                                const float* __restrict__ att,
                                                float* __restrict__ out, int n) {
    int lane = threadIdx.x & 63;
    int node = blockIdx.x * 4 + (threadIdx.x >> 6);
    if (node >= n) return;
    int q = lane & 15;                 // dims 4q..4q+3
    int h = lane >> 4;                 // edge slot 0..3
    int rs = rowstart[node], re = rowstart[node + 1];

    const uint4 zdv = *(const uint4*)(zxb + (size_t)node * 64 + 4 * q);
    hv2 zd01 = u2h(zdv.x), zd23 = u2h(zdv.z);
    float4 av = *(const float4*)(att + 4 * q);
    hv2 at01, at23;
    at01.x = (_Float16)av.x; at01.y = (_Float16)av.y;
    at23.x = (_Float16)av.z; at23.y = (_Float16)av.w;

    hv2 ax01 = (hv2)(_Float16)0.f, ax23 = (hv2)(_Float16)0.f;
    float ssum = 0.f;
    for (int e = rs; e < re; e += 8) {
        int e0i = e + h, e1i = e + 4 + h;
        bool l0 = e0i < re, l1 = e1i < re;
        int s0 = l0 ? srcids[e0i] : node;
        int s1 = l1 ? srcids[e1i] : node;
        const uint4 r0 = *(const uint4*)(zxb + (size_t)s0 * 64 + 4 * q);
        const uint4 r1 = *(const uint4*)(zxb + (size_t)s1 * 64 + 4 * q);

        hv2 v01 = lrelu2(u2h(r0.x) + zd01);
        hv2 v23 = lrelu2(u2h(r0.z) + zd23);
        float p0 = fdot2f(v23, at23, fdot2f(v01, at01, 0.f));

        hv2 w01 = lrelu2(u2h(r1.x) + zd01);
        hv2 w23 = lrelu2(u2h(r1.z) + zd23);
        float p1 = fdot2f(w23, at23, fdot2f(w01, at01, 0.f));

#pragma unroll
        for (int off = 8; off >= 1; off >>= 1) {
            p0 += __shfl_xor(p0, off, 64);
            p1 += __shfl_xor(p1, off, 64);
        }
        float ex0 = l0 ? __builtin_exp2f(p0 * LOG2E) : 0.f;
        float ex1 = l1 ? __builtin_exp2f(p1 * LOG2E) : 0.f;
        ssum += ex0 + ex1;
        hv2 e0h; e0h.x = (_Float16)ex0; e0h.y = (_Float16)ex0;
        hv2 e1h; e1h.x = (_Float16)ex1; e1h.y = (_Float16)ex1;
        ax01 = e0h * u2h(r0.y) + ax01;     // v_pk_fma_f16
        ax23 = e0h * u2h(r0.w) + ax23;
        ax01 = e1h * u2h(r1.y) + ax01;
        ax23 = e1h * u2h(r1.w) + ax23;
    }
    // combine the 4 edge-slots
    ssum += __shfl_xor(ssum, 16, 64); ssum += __shfl_xor(ssum, 32, 64);
    ax01 = ax01 + u2h(__shfl_xor(h2u(ax01), 16, 64));
    ax01 = ax01 + u2h(__shfl_xor(h2u(ax01), 32, 64));
    ax23 = ax23 + u2h(__shfl_xor(h2u(ax23), 16, 64));
    ax23 = ax23 + u2h(__shfl_xor(h2u(ax23), 32, 64));
    if (h == 0) {
        float inv = (re > rs) ? 1.f / ssum : 0.f;
        float4 o = make_float4((float)ax01.x * inv, (float)ax01.y * inv,
                               (float)ax23.x * inv, (float)ax23.y * inv);
        *(float4*)&out[(size_t)node * D + 4 * q] = o;
    }
}

extern "C" void kernel_launch(void* const* d_in, const int* in_sizes, int n_in,
                              void* d_out, int out_size, void* d_ws, size_t ws_size,
                              hipStream_t stream) {
    const float* x   = (const float*)d_in[0];
    const int*   ei  = (const int*)d_in[1];
    const float* W   = (const float*)d_in[2];
    const float* b   = (const float*)d_in[3];
    const float* att = (const float*)d_in[4];
    int n = in_sizes[0] / D;
    int e = in_sizes[1] / 2;
    const int* src = ei;
    const int* dst = ei + e;
    float* out = (float*)d_out;

    int nBlkN   = (n + 255) / 256;      // scan partial blocks (<=512)
    int gemmBlk = (n + 63) / 64;
    int T       = gemmBlk * 256;        // edge-assignment period in gemm_z_count

    // zxb[N*64 uint] | deg8[8N] | rowstart[N+1] | srcids[E] | slot[E] | part[512]
    unsigned int* zxb = (unsigned int*)d_ws;
    int* deg8     = (int*)(zxb + (size_t)n * 64);
    int* rowstart = deg8 + (size_t)NPART * n;
    int* srcids   = rowstart + n + 1;
    int* slot     = srcids + e;
    int* part     = slot + e;

    (void)hipMemsetAsync(deg8, 0, (size_t)NPART * n * sizeof(int), stream);
    gemm_z_count<<<gemmBlk, 256, 0, stream>>>(x, W, b, zxb, n, dst, deg8, slot, e);
    scan_part8<<<nBlkN, 256, 0, stream>>>(deg8, part, n);
    scan_top<<<1, 512, 0, stream>>>(part, nBlkN);
    scan_final8<<<nBlkN, 256, 0, stream>>>(deg8, part, rowstart, n);
    csr_fill_part<<<1024, 256, 0, stream>>>(src, dst, deg8, slot, srcids, e, n, T);
    gather4h<<<(n + 3) / 4, 256, 0, stream>>>(srcids, rowstart, zxb, att, out, n);
}